// Round 2
// baseline (955.704 us; speedup 1.0000x reference)
//
#include <hip/hip_runtime.h>
#include <hip/hip_bf16.h>
#include <math.h>

// Problem constants
#define B_  16
#define LP_ 512
#define LA_ 32
#define DP_ 1024
#define DA_ 512
#define HH_ 512
#define DO_ 1024

// Dtype helpers: MODE 0 = bf16 storage, MODE 1 = f32 storage.
__device__ __forceinline__ float toF(float x){ return x; }
__device__ __forceinline__ float toF(__hip_bfloat16 x){ return __bfloat162float(x); }
__device__ __forceinline__ void stT(float* p, float v){ *p = v; }
__device__ __forceinline__ void stT(__hip_bfloat16* p, float v){ *p = __float2bfloat16(v); }

// ---------------- dtype detector ----------------
// View ppl as bf16 (ushort). If the underlying storage is f32, the even
// halves are raw f32 mantissa bits -> exponent field uniform random ->
// many elements with exponent >= 160 (|x| >= 2^33). Sane bf16 N(0,1) data
// never has exponent >= 160. flag: 0 = bf16 storage, 1 = f32 storage.
__global__ void detect_mode(const unsigned short* __restrict__ raw,
                            int* __restrict__ flag) {
    __shared__ int cnt;
    if (threadIdx.x == 0) cnt = 0;
    __syncthreads();
    int e = (raw[threadIdx.x] >> 7) & 0xFF;
    if (e >= 160) atomicAdd(&cnt, 1);
    __syncthreads();
    if (threadIdx.x == 0) *flag = (cnt > 0) ? 1 : 0;
}

// ---------------- Tiled GEMM: C_f32[M,N] = A[M,K] @ B[K,N] + bias[N]
#define BM 64
#define BN 64
#define BK 16

template<typename T, int MODE>
__global__ __launch_bounds__(256) void gemm_bias(
    const int* __restrict__ flag,
    const T* __restrict__ A,
    const T* __restrict__ Bm,
    const T* __restrict__ bias,
    float* __restrict__ C, int M, int N, int K)
{
    if (*flag != MODE) return;
    __shared__ float As[BK][BM + 1];
    __shared__ float Bs[BK][BN + 1];
    const int tid = threadIdx.x;
    const int nbx = N / BN;
    const int bx = blockIdx.x % nbx;
    const int by = blockIdx.x / nbx;
    const int rowBase = by * BM, colBase = bx * BN;
    const int ty = tid / 16, tx = tid % 16;
    float acc[4][4] = {};

    for (int k0 = 0; k0 < K; k0 += BK) {
        {
            const int am = tid >> 2, ak = (tid & 3) * 4;
            const T* ap = A + (size_t)(rowBase + am) * K + k0 + ak;
#pragma unroll
            for (int j = 0; j < 4; j++) As[ak + j][am] = toF(ap[j]);
        }
        {
            const int bk = tid >> 4, bn = (tid & 15) * 4;
            const T* bp2 = Bm + (size_t)(k0 + bk) * N + colBase + bn;
#pragma unroll
            for (int j = 0; j < 4; j++) Bs[bk][bn + j] = toF(bp2[j]);
        }
        __syncthreads();
#pragma unroll
        for (int kk = 0; kk < BK; kk++) {
            float ra[4], rb[4];
#pragma unroll
            for (int i = 0; i < 4; i++) ra[i] = As[kk][ty * 4 + i];
#pragma unroll
            for (int j = 0; j < 4; j++) rb[j] = Bs[kk][tx * 4 + j];
#pragma unroll
            for (int i = 0; i < 4; i++)
#pragma unroll
                for (int j = 0; j < 4; j++) acc[i][j] += ra[i] * rb[j];
        }
        __syncthreads();
    }
#pragma unroll
    for (int i = 0; i < 4; i++) {
        const int r = rowBase + ty * 4 + i;
#pragma unroll
        for (int j = 0; j < 4; j++) {
            const int c = colBase + tx * 4 + j;
            C[(size_t)r * N + c] = acc[i][j] + toF(bias[c]);
        }
    }
}

// ---------------- Final GEMM: out = relu(concat(ppl, agg) @ Wo + bo)
template<typename T, int MODE>
__global__ __launch_bounds__(256) void gemm_concat_relu(
    const int* __restrict__ flag,
    const T* __restrict__ A0,     // ppl [M, DP_]
    const T* __restrict__ A1,     // agg [M, DA_] (read back from d_out)
    const T* __restrict__ Bm,     // Wo [DP_+DA_, DO_]
    const T* __restrict__ bias,   // bo [DO_]
    T* __restrict__ Out, int M)
{
    if (*flag != MODE) return;
    const int N = DO_, K = DP_ + DA_;
    __shared__ float As[BK][BM + 1];
    __shared__ float Bs[BK][BN + 1];
    const int tid = threadIdx.x;
    const int nbx = N / BN;
    const int bx = blockIdx.x % nbx;
    const int by = blockIdx.x / nbx;
    const int rowBase = by * BM, colBase = bx * BN;
    const int ty = tid / 16, tx = tid % 16;
    float acc[4][4] = {};

    for (int k0 = 0; k0 < K; k0 += BK) {
        {
            const int am = tid >> 2, ak = (tid & 3) * 4;
            const int gk = k0 + ak;  // multiple of 4; never straddles DP_ boundary
            const T* ap = (gk < DP_)
                ? A0 + (size_t)(rowBase + am) * DP_ + gk
                : A1 + (size_t)(rowBase + am) * DA_ + (gk - DP_);
#pragma unroll
            for (int j = 0; j < 4; j++) As[ak + j][am] = toF(ap[j]);
        }
        {
            const int bk = tid >> 4, bn = (tid & 15) * 4;
            const T* bp2 = Bm + (size_t)(k0 + bk) * N + colBase + bn;
#pragma unroll
            for (int j = 0; j < 4; j++) Bs[bk][bn + j] = toF(bp2[j]);
        }
        __syncthreads();
#pragma unroll
        for (int kk = 0; kk < BK; kk++) {
            float ra[4], rb[4];
#pragma unroll
            for (int i = 0; i < 4; i++) ra[i] = As[kk][ty * 4 + i];
#pragma unroll
            for (int j = 0; j < 4; j++) rb[j] = Bs[kk][tx * 4 + j];
#pragma unroll
            for (int i = 0; i < 4; i++)
#pragma unroll
                for (int j = 0; j < 4; j++) acc[i][j] += ra[i] * rb[j];
        }
        __syncthreads();
    }
#pragma unroll
    for (int i = 0; i < 4; i++) {
        const int r = rowBase + ty * 4 + i;
#pragma unroll
        for (int j = 0; j < 4; j++) {
            const int c = colBase + tx * 4 + j;
            float v = acc[i][j] + toF(bias[c]);
            v = v > 0.f ? v : 0.f;
            stT(&Out[(size_t)r * N + c], v);
        }
    }
}

// ---------------- Fused scores -> masked softmax -> agg. One workgroup per (b, p).
template<typename T, int MODE>
__global__ __launch_bounds__(256) void attn_fused(
    const int* __restrict__ flag,
    const float* __restrict__ pa,          // [B*LP, H] f32 (ws)
    const float* __restrict__ an,          // [B*LA, H] f32 (ws)
    const T* __restrict__ answer,          // [B*LA, DA]
    const int* __restrict__ amask,         // [B, LA]
    const T* __restrict__ ww,              // [H]
    const T* __restrict__ wbp,             // [1]
    T* __restrict__ agg_out)               // [B*LP, DA] (d_out tail)
{
    if (*flag != MODE) return;
    __shared__ float s_pa[HH_];
    __shared__ float s_ww[HH_];
    __shared__ float s_sc[LA_];
    __shared__ float s_at[LA_];

    const int bp_idx = blockIdx.x;      // b*LP + p
    const int b = bp_idx >> 9;          // / LP_
    const int tid = threadIdx.x;

    for (int h = tid; h < HH_; h += 256) {
        s_pa[h] = pa[(size_t)bp_idx * HH_ + h];
        s_ww[h] = toF(ww[h]);
    }
    __syncthreads();

    // scores: 32 a-values, 8 lanes each
    const int a = tid >> 3, l = tid & 7;
    const float* anr = an + (size_t)(b * LA_ + a) * HH_;
    float part = 0.f;
    for (int h = l; h < HH_; h += 8)
        part += tanhf(s_pa[h] + anr[h]) * s_ww[h];
    part += __shfl_down(part, 4, 8);
    part += __shfl_down(part, 2, 8);
    part += __shfl_down(part, 1, 8);
    if (l == 0) {
        float sc = part + toF(wbp[0]);
        if (amask[b * LA_ + a] == 0) sc = -1e8f;
        s_sc[a] = sc;
    }
    __syncthreads();

    // softmax over LA_=32 (lanes 0..31 of wave 0)
    if (tid < 32) {
        float s = s_sc[tid];
        float m = s;
        for (int off = 16; off > 0; off >>= 1) m = fmaxf(m, __shfl_xor(m, off, 32));
        float e = expf(s - m);
        float sum = e;
        for (int off = 16; off > 0; off >>= 1) sum += __shfl_xor(sum, off, 32);
        s_at[tid] = e / sum;
    }
    __syncthreads();

    // agg[d] = sum_a attn[a] * answer[b,a,d]
    const T* ansb = answer + (size_t)b * LA_ * DA_;
    for (int d = tid; d < DA_; d += 256) {
        float acc = 0.f;
#pragma unroll
        for (int a2 = 0; a2 < LA_; a2++)
            acc += s_at[a2] * toF(ansb[a2 * DA_ + d]);
        stT(&agg_out[(size_t)bp_idx * DA_ + d], acc);
    }
}

extern "C" void kernel_launch(void* const* d_in, const int* in_sizes, int n_in,
                              void* d_out, int out_size, void* d_ws, size_t ws_size,
                              hipStream_t stream) {
    const int* amask = (const int*)d_in[3];

    // Workspace layout: [0..3] flag int, [16..] pa f32 [8192,512], then an f32 [512,512]
    int*   flag  = (int*)d_ws;
    float* pa_ws = (float*)((char*)d_ws + 16);
    float* an_ws = pa_ws + (size_t)B_ * LP_ * HH_;

    const int M1 = B_ * LA_;   // 512
    const int M2 = B_ * LP_;   // 8192

    // Detect storage dtype from ppl's raw bits.
    detect_mode<<<1, 1024, 0, stream>>>((const unsigned short*)d_in[0], flag);

    // ---- bf16-mode instantiation (MODE 0) ----
    {
        const __hip_bfloat16* ppl    = (const __hip_bfloat16*)d_in[0];
        const __hip_bfloat16* answer = (const __hip_bfloat16*)d_in[2];
        const __hip_bfloat16* Wp     = (const __hip_bfloat16*)d_in[4];
        const __hip_bfloat16* bp     = (const __hip_bfloat16*)d_in[5];
        const __hip_bfloat16* Wa     = (const __hip_bfloat16*)d_in[6];
        const __hip_bfloat16* ba     = (const __hip_bfloat16*)d_in[7];
        const __hip_bfloat16* ww     = (const __hip_bfloat16*)d_in[8];
        const __hip_bfloat16* wb     = (const __hip_bfloat16*)d_in[9];
        const __hip_bfloat16* Wo     = (const __hip_bfloat16*)d_in[10];
        const __hip_bfloat16* bo     = (const __hip_bfloat16*)d_in[11];
        __hip_bfloat16* aligned_out = (__hip_bfloat16*)d_out;
        __hip_bfloat16* agg_out     = aligned_out + (size_t)B_ * LP_ * DP_;

        gemm_bias<__hip_bfloat16, 0><<<(M1 / BM) * (HH_ / BN), 256, 0, stream>>>(
            flag, answer, Wa, ba, an_ws, M1, HH_, DA_);
        gemm_bias<__hip_bfloat16, 0><<<(M2 / BM) * (HH_ / BN), 256, 0, stream>>>(
            flag, ppl, Wp, bp, pa_ws, M2, HH_, DP_);
        attn_fused<__hip_bfloat16, 0><<<M2, 256, 0, stream>>>(
            flag, pa_ws, an_ws, answer, amask, ww, wb, agg_out);
        gemm_concat_relu<__hip_bfloat16, 0><<<(M2 / BM) * (DO_ / BN), 256, 0, stream>>>(
            flag, ppl, agg_out, Wo, bo, aligned_out, M2);
    }

    // ---- f32-mode instantiation (MODE 1) ----
    {
        const float* ppl    = (const float*)d_in[0];
        const float* answer = (const float*)d_in[2];
        const float* Wp     = (const float*)d_in[4];
        const float* bp     = (const float*)d_in[5];
        const float* Wa     = (const float*)d_in[6];
        const float* ba     = (const float*)d_in[7];
        const float* ww     = (const float*)d_in[8];
        const float* wb     = (const float*)d_in[9];
        const float* Wo     = (const float*)d_in[10];
        const float* bo     = (const float*)d_in[11];
        float* aligned_out = (float*)d_out;
        float* agg_out     = aligned_out + (size_t)B_ * LP_ * DP_;

        gemm_bias<float, 1><<<(M1 / BM) * (HH_ / BN), 256, 0, stream>>>(
            flag, answer, Wa, ba, an_ws, M1, HH_, DA_);
        gemm_bias<float, 1><<<(M2 / BM) * (HH_ / BN), 256, 0, stream>>>(
            flag, ppl, Wp, bp, pa_ws, M2, HH_, DP_);
        attn_fused<float, 1><<<M2, 256, 0, stream>>>(
            flag, pa_ws, an_ws, answer, amask, ww, wb, agg_out);
        gemm_concat_relu<float, 1><<<(M2 / BM) * (DO_ / BN), 256, 0, stream>>>(
            flag, ppl, agg_out, Wo, bo, aligned_out, M2);
    }
}